// Round 1
// baseline (22.208 us; speedup 1.0000x reference)
//
#include <hip/hip_runtime.h>
#include <math.h>

#define TPB 256

// RY on the qubit whose index-bit mask is M (wire0->8, wire1->4, wire2->2, wire3->1)
template <int M>
__device__ inline void ry16(float st[16], float C, float S) {
#pragma unroll
    for (int idx = 0; idx < 16; ++idx) {
        if (!(idx & M)) {
            float a = st[idx], b = st[idx | M];
            st[idx]     = C * a - S * b;
            st[idx | M] = S * a + C * b;
        }
    }
}

__global__ __launch_bounds__(TPB) void quanv_fused_kernel(
    const float* __restrict__ x,       // (B, 784)
    const float* __restrict__ params,  // (L, 4)
    const float* __restrict__ W,       // (10, 1568)
    const float* __restrict__ bias,    // (10,)
    float* __restrict__ out,           // (B, 10)
    int L)
{
    __shared__ float img[784];
    __shared__ float feats[1568];
    __shared__ float pco[64], psi[64];   // param cos/sin (L <= 16)
    __shared__ float red[4][10];

    const int b   = blockIdx.x;
    const int tid = threadIdx.x;
    const float* xb = x + (size_t)b * 784;

    // ---- load image, precompute param sin/cos ----
    for (int q = tid; q < 784; q += TPB) img[q] = xb[q];
    for (int k = tid; k < 4 * L; k += TPB) {
        float s, c;
        sincosf(params[k] * 0.5f, &s, &c);
        pco[k] = c; psi[k] = s;
    }
    __syncthreads();

    // ---- classical features: feats[784 + ((a*4+b)*7+i)*7+j] = img[(i*4+a)*28 + (j*4+b)] ----
    for (int q = tid; q < 784; q += TPB) {
        int row = q / 28, col = q - row * 28;
        int a = row & 3, i = row >> 2;
        int bb = col & 3, j = col >> 2;
        feats[784 + ((a * 4 + bb) * 7 + i) * 7 + j] = img[q];
    }

    // ---- quantum features: one patch per thread (196 patches) ----
    if (tid < 196) {
        int pi = tid / 14, pj = tid - pi * 14;
        float v0 = img[(2 * pi) * 28 + 2 * pj];
        float v1 = img[(2 * pi) * 28 + 2 * pj + 1];
        float v2 = img[(2 * pi + 1) * 28 + 2 * pj];
        float v3 = img[(2 * pi + 1) * 28 + 2 * pj + 1];

        float c0, s0, c1, s1, c2, s2, c3, s3;
        sincosf(v0 * 0.5f, &s0, &c0);
        sincosf(v1 * 0.5f, &s1, &c1);
        sincosf(v2 * 0.5f, &s2, &c2);
        sincosf(v3 * 0.5f, &s3, &c3);

        // product state after the 4 data RYs: st[w0*8+w1*4+w2*2+w3]
        float st[16];
#pragma unroll
        for (int w0 = 0; w0 < 2; ++w0) {
            float a0 = w0 ? s0 : c0;
#pragma unroll
            for (int w1 = 0; w1 < 2; ++w1) {
                float a01 = a0 * (w1 ? s1 : c1);
#pragma unroll
                for (int w2 = 0; w2 < 2; ++w2) {
                    float a012 = a01 * (w2 ? s2 : c2);
#pragma unroll
                    for (int w3 = 0; w3 < 2; ++w3) {
                        st[w0 * 8 + w1 * 4 + w2 * 2 + w3] = a012 * (w3 ? s3 : c3);
                    }
                }
            }
        }

        // variational layers
        for (int l = 0; l < L; ++l) {
            ry16<8>(st, pco[l * 4 + 0], psi[l * 4 + 0]);  // RY wire0
            ry16<4>(st, pco[l * 4 + 1], psi[l * 4 + 1]);  // RY wire1
            // CNOT(control=0, target=1): for bit3 set, swap bit2
#pragma unroll
            for (int r = 0; r < 4; ++r) {
                float t = st[8 + r]; st[8 + r] = st[12 + r]; st[12 + r] = t;
            }
            ry16<2>(st, pco[l * 4 + 2], psi[l * 4 + 2]);  // RY wire2
            ry16<1>(st, pco[l * 4 + 3], psi[l * 4 + 3]);  // RY wire3
            // CNOT(control=2, target=3): for bit1 set, swap bit0
#pragma unroll
            for (int base = 2; base < 16; base += 4) {
                float t = st[base]; st[base] = st[base + 1]; st[base + 1] = t;
            }
        }

        // expectation values <Z_w>
        float z0 = 0.f, z1 = 0.f, z2 = 0.f, z3 = 0.f;
#pragma unroll
        for (int idx = 0; idx < 16; ++idx) {
            float p = st[idx] * st[idx];
            z0 += (idx & 8) ? -p : p;
            z1 += (idx & 4) ? -p : p;
            z2 += (idx & 2) ? -p : p;
            z3 += (idx & 1) ? -p : p;
        }
        feats[tid * 4 + 0] = z0;
        feats[tid * 4 + 1] = z1;
        feats[tid * 4 + 2] = z2;
        feats[tid * 4 + 3] = z3;
    }
    __syncthreads();

    // ---- linear layer: acc[c] = sum_f feats[f] * W[c][f] (coalesced W reads) ----
    float acc[10];
#pragma unroll
    for (int c = 0; c < 10; ++c) acc[c] = 0.f;
    for (int f = tid; f < 1568; f += TPB) {
        float v = feats[f];
#pragma unroll
        for (int c = 0; c < 10; ++c) acc[c] += v * W[c * 1568 + f];
    }

    // ---- block reduction ----
    const int lane = tid & 63;
    const int wave = tid >> 6;
#pragma unroll
    for (int c = 0; c < 10; ++c) {
        float v = acc[c];
#pragma unroll
        for (int off = 32; off > 0; off >>= 1) v += __shfl_down(v, off, 64);
        if (lane == 0) red[wave][c] = v;
    }
    __syncthreads();

    // ---- bias + log_softmax + write ----
    if (tid == 0) {
        float lg[10];
#pragma unroll
        for (int c = 0; c < 10; ++c)
            lg[c] = red[0][c] + red[1][c] + red[2][c] + red[3][c] + bias[c];
        float m = lg[0];
#pragma unroll
        for (int c = 1; c < 10; ++c) m = fmaxf(m, lg[c]);
        float se = 0.f;
#pragma unroll
        for (int c = 0; c < 10; ++c) se += expf(lg[c] - m);
        float lse = logf(se);
#pragma unroll
        for (int c = 0; c < 10; ++c) out[b * 10 + c] = lg[c] - m - lse;
    }
}

extern "C" void kernel_launch(void* const* d_in, const int* in_sizes, int n_in,
                              void* d_out, int out_size, void* d_ws, size_t ws_size,
                              hipStream_t stream) {
    const float* x      = (const float*)d_in[0];
    const float* params = (const float*)d_in[1];
    const float* W      = (const float*)d_in[2];
    const float* bias   = (const float*)d_in[3];
    float* out          = (float*)d_out;

    const int B = in_sizes[0] / 784;
    const int L = in_sizes[1] / 4;

    quanv_fused_kernel<<<dim3(B), dim3(TPB), 0, stream>>>(x, params, W, bias, out, L);
}

// Round 2
// 18.092 us; speedup vs baseline: 1.2276x; 1.2276x over previous
//
#include <hip/hip_runtime.h>
#include <math.h>

#define TPB 256

// Fused quanvolution forward. Key insight: the 4-qubit circuit only entangles
// wire pairs {0,1} and {2,3} (CNOT(0,1) and CNOT(2,3) only), so the state is
// a tensor product of two 2-qubit states (4 real amplitudes each).
// <Z0>,<Z1> depend only on the {0,1} factor; <Z2>,<Z3> only on {2,3}.

template <int LC>
__global__ __launch_bounds__(TPB) void quanv_fused_kernel(
    const float* __restrict__ x,       // (B, 784)
    const float* __restrict__ params,  // (L, 4)
    const float* __restrict__ W,       // (10, 1568)
    const float* __restrict__ bias,    // (10,)
    float* __restrict__ out,           // (B, 10)
    int Lrt)
{
    const int L = (LC > 0) ? LC : Lrt;

    __shared__ float img[784];
    __shared__ float feats[1568];
    __shared__ float pco[64], psi[64];   // param cos/sin (L <= 16)
    __shared__ float red[4][10];

    const int b   = blockIdx.x;
    const int tid = threadIdx.x;
    const float* xb = x + (size_t)b * 784;

    // ---- load image (float4) ; threads 196+ precompute param sin/cos ----
    if (tid < 196) {
        ((float4*)img)[tid] = ((const float4*)xb)[tid];
    } else {
        int k = tid - 196;
        if (k < 4 * L) {
            float s, c;
            sincosf(params[k] * 0.5f, &s, &c);
            pco[k] = c; psi[k] = s;
        }
    }
    __syncthreads();

    // ---- classical features: feats[784 + ((a*4+b)*7+i)*7+j] = img[(i*4+a)*28 + (j*4+b)] ----
    for (int q = tid; q < 784; q += TPB) {
        int row = q / 28, col = q - row * 28;
        int a = row & 3, i = row >> 2;
        int bb = col & 3, j = col >> 2;
        feats[784 + ((a * 4 + bb) * 7 + i) * 7 + j] = img[q];
    }

    // ---- quantum features: one patch per thread (196 patches) ----
    if (tid < 196) {
        int pi = tid / 14, pj = tid - pi * 14;
        const float* r0 = &img[2 * pi * 28 + 2 * pj];
        float x0 = r0[0], x1 = r0[1], x2 = r0[28], x3 = r0[29];

        float c0 = __cosf(0.5f * x0), s0 = __sinf(0.5f * x0);
        float c1 = __cosf(0.5f * x1), s1 = __sinf(0.5f * x1);
        float c2 = __cosf(0.5f * x2), s2 = __sinf(0.5f * x2);
        float c3 = __cosf(0.5f * x3), s3 = __sinf(0.5f * x3);

        // two independent 2-qubit states: u = wires{0,1}, v = wires{2,3}
        // index = wireHi*2 + wireLo
        float u0 = c0 * c1, u1 = c0 * s1, u2 = s0 * c1, u3 = s0 * s1;
        float v0 = c2 * c3, v1 = c2 * s3, v2 = s2 * c3, v3 = s2 * s3;

#pragma unroll
        for (int l = 0; l < L; ++l) {
            float C, S, t0, t1, t2, t3, tmp;
            // RY(params[l,0]) on wire0 of u: pairs (u0,u2),(u1,u3)
            C = pco[4 * l + 0]; S = psi[4 * l + 0];
            t0 = C * u0 - S * u2;  t2 = S * u0 + C * u2;
            t1 = C * u1 - S * u3;  t3 = S * u1 + C * u3;
            // RY(params[l,1]) on wire1 of u: pairs (t0,t1),(t2,t3)
            C = pco[4 * l + 1]; S = psi[4 * l + 1];
            u0 = C * t0 - S * t1;  u1 = S * t0 + C * t1;
            u2 = C * t2 - S * t3;  u3 = S * t2 + C * t3;
            // CNOT(0->1): where wire0==1, flip wire1 -> swap u2,u3
            tmp = u2; u2 = u3; u3 = tmp;

            // RY(params[l,2]) on wire2 of v
            C = pco[4 * l + 2]; S = psi[4 * l + 2];
            t0 = C * v0 - S * v2;  t2 = S * v0 + C * v2;
            t1 = C * v1 - S * v3;  t3 = S * v1 + C * v3;
            // RY(params[l,3]) on wire3 of v
            C = pco[4 * l + 3]; S = psi[4 * l + 3];
            v0 = C * t0 - S * t1;  v1 = S * t0 + C * t1;
            v2 = C * t2 - S * t3;  v3 = S * t2 + C * t3;
            // CNOT(2->3): swap v2,v3
            tmp = v2; v2 = v3; v3 = tmp;
        }

        float p0 = u0 * u0, p1 = u1 * u1, p2 = u2 * u2, p3 = u3 * u3;
        float q0 = v0 * v0, q1 = v1 * v1, q2 = v2 * v2, q3 = v3 * v3;
        float z0 = (p0 + p1) - (p2 + p3);
        float z1 = (p0 + p2) - (p1 + p3);
        float z2 = (q0 + q1) - (q2 + q3);
        float z3 = (q0 + q2) - (q1 + q3);

        ((float4*)feats)[tid] = make_float4(z0, z1, z2, z3);
    }
    __syncthreads();

    // ---- linear layer: acc[c] = sum_f feats[f] * W[c][f] (coalesced W reads) ----
    float acc[10];
#pragma unroll
    for (int c = 0; c < 10; ++c) acc[c] = 0.f;
#pragma unroll
    for (int k = 0; k < 6; ++k) {
        int f = tid + k * TPB;
        float v = feats[f];
#pragma unroll
        for (int c = 0; c < 10; ++c) acc[c] = fmaf(v, W[c * 1568 + f], acc[c]);
    }
    if (tid < 32) {  // 1568 = 6*256 + 32
        int f = tid + 1536;
        float v = feats[f];
#pragma unroll
        for (int c = 0; c < 10; ++c) acc[c] = fmaf(v, W[c * 1568 + f], acc[c]);
    }

    // ---- block reduction ----
    const int lane = tid & 63;
    const int wave = tid >> 6;
#pragma unroll
    for (int c = 0; c < 10; ++c) {
        float v = acc[c];
#pragma unroll
        for (int off = 32; off > 0; off >>= 1) v += __shfl_down(v, off, 64);
        if (lane == 0) red[wave][c] = v;
    }
    __syncthreads();

    // ---- bias + log_softmax + write ----
    if (tid == 0) {
        float lg[10];
#pragma unroll
        for (int c = 0; c < 10; ++c)
            lg[c] = red[0][c] + red[1][c] + red[2][c] + red[3][c] + bias[c];
        float m = lg[0];
#pragma unroll
        for (int c = 1; c < 10; ++c) m = fmaxf(m, lg[c]);
        float se = 0.f;
#pragma unroll
        for (int c = 0; c < 10; ++c) se += expf(lg[c] - m);
        float lse = logf(se);
#pragma unroll
        for (int c = 0; c < 10; ++c) out[b * 10 + c] = lg[c] - m - lse;
    }
}

extern "C" void kernel_launch(void* const* d_in, const int* in_sizes, int n_in,
                              void* d_out, int out_size, void* d_ws, size_t ws_size,
                              hipStream_t stream) {
    const float* x      = (const float*)d_in[0];
    const float* params = (const float*)d_in[1];
    const float* W      = (const float*)d_in[2];
    const float* bias   = (const float*)d_in[3];
    float* out          = (float*)d_out;

    const int B = in_sizes[0] / 784;
    const int L = in_sizes[1] / 4;

    if (L == 4) {
        quanv_fused_kernel<4><<<dim3(B), dim3(TPB), 0, stream>>>(x, params, W, bias, out, L);
    } else {
        quanv_fused_kernel<0><<<dim3(B), dim3(TPB), 0, stream>>>(x, params, W, bias, out, L);
    }
}